// Round 2
// baseline (1942.989 us; speedup 1.0000x reference)
//
#include <hip/hip_runtime.h>
#include <math.h>

typedef float v2f __attribute__((ext_vector_type(2)));

__device__ __forceinline__ float bf2f(ushort u) {
  union { unsigned int i; float f; } v; v.i = ((unsigned int)u) << 16; return v.f;
}
__device__ __forceinline__ ushort f2bf(float f) {
  union { float f; unsigned int i; } v; v.f = f;
  unsigned int x = v.i;
  return (ushort)((x + 0x7fffu + ((x >> 16) & 1u)) >> 16);  // RNE
}
// uint holding two bf16 (mem order: low ushort = even k) -> v2f {even, odd}
__device__ __forceinline__ v2f bfp(unsigned int u) {
  union { unsigned int i; float f; } lo, hi;
  lo.i = u << 16; hi.i = u & 0xffff0000u;
  v2f r; r.x = lo.f; r.y = hi.f; return r;
}

// C = A[32 tok x 96 k] * W[96 k x 96 col], K-pair-interleaved bf16 LDS layouts:
//   A: [(k2*32 + tok)*2 + (k&1)]   W: [(k2*96 + col)*2 + (k&1)]
// Thread (tg,cg) accumulates 4 tok x 3 col; acc.x holds even-k sum, acc.y odd-k.
__device__ __forceinline__ void gemm48(const ushort* __restrict__ A,
                                       const ushort* __restrict__ W,
                                       v2f acc[4][3], int tg, int cg) {
#pragma unroll 4
  for (int k2 = 0; k2 < 48; ++k2) {
    uint4 av = *(const uint4*)(A + (k2 * 32 + tg * 4) * 2);
    unsigned int bu0 = *(const unsigned int*)(W + (k2 * 96 + cg * 3 + 0) * 2);
    unsigned int bu1 = *(const unsigned int*)(W + (k2 * 96 + cg * 3 + 1) * 2);
    unsigned int bu2 = *(const unsigned int*)(W + (k2 * 96 + cg * 3 + 2) * 2);
    v2f a0 = bfp(av.x), a1 = bfp(av.y), a2 = bfp(av.z), a3 = bfp(av.w);
    v2f b0 = bfp(bu0), b1 = bfp(bu1), b2 = bfp(bu2);
    acc[0][0] += a0 * b0; acc[0][1] += a0 * b1; acc[0][2] += a0 * b2;
    acc[1][0] += a1 * b0; acc[1][1] += a1 * b1; acc[1][2] += a1 * b2;
    acc[2][0] += a2 * b0; acc[2][1] += a2 * b1; acc[2][2] += a2 * b2;
    acc[3][0] += a3 * b0; acc[3][1] += a3 * b1; acc[3][2] += a3 * b2;
  }
}

// stage 96x96 fp32 weight tile from gsrc[k*ld + jj] into interleaved bf16 Ws2
__device__ __forceinline__ void stageW(ushort* __restrict__ Ws2,
                                       const float* __restrict__ gsrc,
                                       int ld, int tid) {
  for (int i = tid; i < 9216; i += 256) {
    int k = i / 96, jj = i - k * 96;
    Ws2[((k >> 1) * 96 + jj) * 2 + (k & 1)] = f2bf(gsrc[k * ld + jj]);
  }
}

__global__ __launch_bounds__(256, 3) void swin_fused(
    const float* __restrict__ x,
    const float* __restrict__ qkv_w, const float* __restrict__ qkv_b,
    const float* __restrict__ merge_w, const float* __restrict__ merge_b,
    const float* __restrict__ w1, const float* __restrict__ b1,
    const float* __restrict__ w2, const float* __restrict__ b2,
    float* __restrict__ out) {
  // LDS: 6144 + 19584 + 6144 + 18432 = 50304 B -> 3 blocks/CU
  __shared__ __align__(16) ushort XsT2[96 * 32];    // X, interleaved A layout
  __shared__ __align__(16) ushort QKVsT[288 * 34];  // [col][tok], pad 34; reused as Hmid (interleaved)
  __shared__ __align__(16) ushort MSGsT2[96 * 32];  // msg, interleaved; reused as Out [col*32+tok]
  __shared__ __align__(16) ushort Ws2[96 * 96];     // weight chunk, interleaved

  const int tid = threadIdx.x;
  const int bid = blockIdx.x;
  const int t4 = bid & 7;          // t base = t4*8 (4 windows along t)
  const int w0 = (bid >> 3) & 31;
  const int h0 = (bid >> 8) & 31;
  const int b = bid >> 13;

  // ---- P1: load X tile: per (c,dh,dw,half) one float4 (4 contiguous t) ----
  for (int i = tid; i < 768; i += 256) {
    int c = i >> 3, rem = i & 7;
    int dh = rem >> 2, dw = (rem >> 1) & 1, half = rem & 1;
    size_t gidx = ((((size_t)b * 96 + c) * 64 + h0 * 2 + dh) * 64 + w0 * 2 + dw) * 64 + t4 * 8 + half * 4;
    float4 ld = *(const float4*)(x + gidx);
    float vals[4] = {ld.x, ld.y, ld.z, ld.w};
#pragma unroll
    for (int j = 0; j < 4; ++j) {
      // token-in-block = wi*8 + (dh,dw,dt);  wi = half*2 + (j>>1), dt = j&1
      int tok = (half * 2 + (j >> 1)) * 8 + dh * 4 + dw * 2 + (j & 1);
      XsT2[((c >> 1) * 32 + tok) * 2 + (c & 1)] = f2bf(vals[j]);
    }
  }
  __syncthreads();

  const int tg = tid >> 5;  // 4-token group
  const int cg = tid & 31;  // 3-col group

  // ---- P2: QKV = X @ qkv_w + qkv_b  (3 chunks of 96 cols) ----
  for (int cn = 0; cn < 3; ++cn) {
    stageW(Ws2, qkv_w + cn * 96, 288, tid);
    __syncthreads();
    v2f acc[4][3] = {};
    gemm48(XsT2, Ws2, acc, tg, cg);
#pragma unroll
    for (int i2 = 0; i2 < 4; ++i2)
#pragma unroll
      for (int j = 0; j < 3; ++j) {
        int col = cn * 96 + cg * 3 + j;
        float r = acc[i2][j].x + acc[i2][j].y + qkv_b[col];
        QKVsT[col * 34 + tg * 4 + i2] = f2bf(r);
      }
    __syncthreads();
  }

  // ---- P3: windowed attention (thread = (window, head, query row)) ----
  {
    const int pair = tid >> 3;   // 0..31
    const int r = tid & 7;       // query row
    const int wi = pair >> 3;    // window 0..3
    const int head = pair & 7;
    const int tq = wi * 8 + r;
    const float scale = 0.28867513459481287f;  // 1/sqrt(12)
    float q[12];
#pragma unroll
    for (int d = 0; d < 12; ++d) q[d] = bf2f(QKVsT[(head * 12 + d) * 34 + tq]);
    float s[8];
#pragma unroll
    for (int m = 0; m < 8; ++m) {
      float a = 0.f;
#pragma unroll
      for (int d = 0; d < 12; ++d)
        a += q[d] * bf2f(QKVsT[(96 + head * 12 + d) * 34 + wi * 8 + m]);
      s[m] = a * scale;
    }
    float mx = s[0];
#pragma unroll
    for (int m = 1; m < 8; ++m) mx = fmaxf(mx, s[m]);
    float sum = 0.f;
#pragma unroll
    for (int m = 0; m < 8; ++m) { s[m] = __expf(s[m] - mx); sum += s[m]; }
    float inv = 1.0f / sum;
    float o[12] = {};
#pragma unroll
    for (int m = 0; m < 8; ++m) {
      float p = s[m] * inv;
#pragma unroll
      for (int d = 0; d < 12; ++d)
        o[d] += p * bf2f(QKVsT[(192 + head * 12 + d) * 34 + wi * 8 + m]);
    }
#pragma unroll
    for (int d = 0; d < 12; ++d) {
      int col = head * 12 + d;
      MSGsT2[((col >> 1) * 32 + tq) * 2 + (col & 1)] = f2bf(o[d]);
    }
  }
  __syncthreads();

  // ---- P4: msg = msg @ merge_w + merge_b (in place) ----
  {
    stageW(Ws2, merge_w, 96, tid);
    __syncthreads();
    v2f acc[4][3] = {};
    gemm48(MSGsT2, Ws2, acc, tg, cg);
    float res[4][3];
#pragma unroll
    for (int i2 = 0; i2 < 4; ++i2)
#pragma unroll
      for (int j = 0; j < 3; ++j)
        res[i2][j] = acc[i2][j].x + acc[i2][j].y + merge_b[cg * 3 + j];
    __syncthreads();  // all reads of MSGsT2 done before overwrite
#pragma unroll
    for (int i2 = 0; i2 < 4; ++i2)
#pragma unroll
      for (int j = 0; j < 3; ++j) {
        int col = cg * 3 + j;
        MSGsT2[((col >> 1) * 32 + tg * 4 + i2) * 2 + (col & 1)] = f2bf(res[i2][j]);
      }
    __syncthreads();
  }

  // ---- P5: hmid = gelu([X, msg] @ w1 + b1) -> QKV region ----
  {
    stageW(Ws2, w1, 96, tid);
    __syncthreads();
    v2f acc[4][3] = {};
    gemm48(XsT2, Ws2, acc, tg, cg);
    __syncthreads();  // gemm reads of Ws2 done before restage
    stageW(Ws2, w1 + 96 * 96, 96, tid);
    __syncthreads();
    gemm48(MSGsT2, Ws2, acc, tg, cg);
    ushort* HsT2 = QKVsT;
#pragma unroll
    for (int i2 = 0; i2 < 4; ++i2)
#pragma unroll
      for (int j = 0; j < 3; ++j) {
        int col = cg * 3 + j;
        float h = acc[i2][j].x + acc[i2][j].y + b1[col];
        float g = 0.5f * h * (1.0f + erff(h * 0.70710678118654752f));
        HsT2[((col >> 1) * 32 + tg * 4 + i2) * 2 + (col & 1)] = f2bf(g);
      }
    __syncthreads();
  }

  // ---- P6: out = hmid @ w2 + b2 -> OsT [col*32+tok] ----
  {
    stageW(Ws2, w2, 96, tid);
    __syncthreads();
    v2f acc[4][3] = {};
    gemm48(QKVsT /*HsT2*/, Ws2, acc, tg, cg);
    ushort* OsT = MSGsT2;
#pragma unroll
    for (int i2 = 0; i2 < 4; ++i2)
#pragma unroll
      for (int j = 0; j < 3; ++j) {
        int col = cg * 3 + j;
        float r = acc[i2][j].x + acc[i2][j].y + b2[col];
        OsT[col * 32 + tg * 4 + i2] = f2bf(r);
      }
    __syncthreads();
  }

  // ---- P7: pack 4 t-contiguous outputs per (c,dh,dw,half), one float4 store ----
  for (int i = tid; i < 768; i += 256) {
    int c = i >> 3, rem = i & 7;
    int dh = rem >> 2, dw = (rem >> 1) & 1, half = rem & 1;
    float4 st;
    float vals[4];
#pragma unroll
    for (int j = 0; j < 4; ++j) {
      int tok = (half * 2 + (j >> 1)) * 8 + dh * 4 + dw * 2 + (j & 1);
      vals[j] = bf2f(MSGsT2[c * 32 + tok]);
    }
    st.x = vals[0]; st.y = vals[1]; st.z = vals[2]; st.w = vals[3];
    size_t gidx = ((((size_t)b * 96 + c) * 64 + h0 * 2 + dh) * 64 + w0 * 2 + dw) * 64 + t4 * 8 + half * 4;
    *(float4*)(out + gidx) = st;
  }
}

extern "C" void kernel_launch(void* const* d_in, const int* in_sizes, int n_in,
                              void* d_out, int out_size, void* d_ws, size_t ws_size,
                              hipStream_t stream) {
  const float* x = (const float*)d_in[0];
  const float* qkv_w = (const float*)d_in[1];
  const float* qkv_b = (const float*)d_in[2];
  const float* merge_w = (const float*)d_in[3];
  const float* merge_b = (const float*)d_in[4];
  const float* w1 = (const float*)d_in[5];
  const float* b1 = (const float*)d_in[6];
  const float* w2 = (const float*)d_in[7];
  const float* b2 = (const float*)d_in[8];
  float* out = (float*)d_out;
  // grid: B(2) * h0(32) * w0(32) * t4(8) = 16384 blocks of 256 threads
  swin_fused<<<dim3(16384), dim3(256), 0, stream>>>(
      x, qkv_w, qkv_b, merge_w, merge_b, w1, b1, w2, b2, out);
}

// Round 3
// 616.397 us; speedup vs baseline: 3.1522x; 3.1522x over previous
//
#include <hip/hip_runtime.h>
#include <math.h>

typedef short bf16x8 __attribute__((ext_vector_type(8)));
typedef float f32x4 __attribute__((ext_vector_type(4)));

__device__ __forceinline__ ushort f2bf(float f) {
  union { float f; unsigned int i; } v; v.f = f;
  unsigned int x = v.i;
  return (ushort)((x + 0x7fffu + ((x >> 16) & 1u)) >> 16);  // RNE
}
__device__ __forceinline__ float bf2f(ushort u) {
  union { unsigned int i; float f; } v; v.i = ((unsigned int)u) << 16; return v.f;
}

// async global->LDS, 16B per lane; lds addr must be uniform + lane*16 (it is:
// callers pass l + (tid + j*256)*8 ushorts = waveuniform + lane*16 bytes).
__device__ __forceinline__ void cp16(const ushort* g, ushort* l) {
  __builtin_amdgcn_global_load_lds(
      (const __attribute__((address_space(1))) void*)g,
      (__attribute__((address_space(3))) void*)l, 16, 0, 0);
}
// stage one 96x96 bf16 fragment-swizzled chunk (18432 B = 1152 x 16B)
__device__ __forceinline__ void stage_chunk(const ushort* __restrict__ g,
                                            ushort* l, int tid) {
  for (int i = tid; i < 1152; i += 256) cp16(g + i * 8, l + i * 8);
}

// ---------------- pre-kernel: swizzle weights to B-fragment tiles ----------
// tile = 16 cols x 32 k = 64 lanes x 8 bf16 (lane holds B[k0+(l>>4)*8+j][n0+(l&15)])
// d_ws tiles: [0,54) qkv (3 chunks x 6nt x 3kt), [54,72) merge, [72,90) w1a,
// [90,108) w1b (k offset 96), [108,126) w2.  126 tiles x 1024 B = 129024 B.
__global__ void swizzle_w(const float* __restrict__ qkv_w,
                          const float* __restrict__ merge_w,
                          const float* __restrict__ w1,
                          const float* __restrict__ w2,
                          ushort* __restrict__ ws) {
  int g = blockIdx.x * 256 + threadIdx.x;
  if (g >= 8064) return;  // 126 tiles * 64 lanes
  int tile = g >> 6, lane = g & 63;
  const float* src; int ld, c0, k0, rem;
  if (tile < 54)       { rem = tile % 18; src = qkv_w;   ld = 288; c0 = (tile / 18) * 96 + (rem / 3) * 16; k0 = (rem % 3) * 32; }
  else if (tile < 72)  { rem = tile - 54; src = merge_w; ld = 96;  c0 = (rem / 3) * 16; k0 = (rem % 3) * 32; }
  else if (tile < 90)  { rem = tile - 72; src = w1;      ld = 96;  c0 = (rem / 3) * 16; k0 = (rem % 3) * 32; }
  else if (tile < 108) { rem = tile - 90; src = w1;      ld = 96;  c0 = (rem / 3) * 16; k0 = 96 + (rem % 3) * 32; }
  else                 { rem = tile - 108; src = w2;     ld = 96;  c0 = (rem / 3) * 16; k0 = (rem % 3) * 32; }
  int n = c0 + (lane & 15);
  int kb = k0 + (lane >> 4) * 8;
  ushort tmp[8];
#pragma unroll
  for (int j = 0; j < 8; ++j) tmp[j] = f2bf(src[(size_t)(kb + j) * ld + n]);
  *(uint4*)(ws + tile * 512 + lane * 8) = *(const uint4*)tmp;
}

// ---------------- main fused kernel ----------------------------------------
// block: 64 tokens = (2h x 2w) x 16t = 8 windows along t. 4 waves, wave w owns
// tokens [16w,16w+16). A-tiles in LDS [tok][k] stride 104 bf16; B from Ws
// fragment-swizzled (ds_read_b128 at lane*16, conflict-free).
#define KPAD 104
#define QPAD 66   // QKV [col 0..287][tok] stride
#define OPAD 65   // out [col 0..95][tok] stride
__global__ __launch_bounds__(256, 2) void swin_mfma(
    const float* __restrict__ x,
    const float* __restrict__ qkv_b, const float* __restrict__ merge_b,
    const float* __restrict__ b1, const float* __restrict__ b2,
    const ushort* __restrict__ wsw, float* __restrict__ out) {
  __shared__ __align__(16) ushort Xs[64 * KPAD];  // 13312 B
  __shared__ __align__(16) ushort R[19008];       // 38016 B: QKV -> msg/hmid/out
  __shared__ __align__(16) ushort Ws[9216];       // 18432 B weight chunk

  const int tid = threadIdx.x, bid = blockIdx.x;
  const int t0 = bid & 3, w0 = (bid >> 2) & 31, h0 = (bid >> 7) & 31, b = bid >> 12;
  const int lane = tid & 63, wave = tid >> 6;
  const int mrow = lane & 15, quad = lane >> 4;
  const int arow = (wave * 16 + mrow) * KPAD + quad * 8;  // A-frag base (elems)
  const int tokb = wave * 16 + quad * 4;                  // C-frag row base

  // P1: x -> Xs[tok][c] bf16 (coalesced float4 along t)
  for (int i = tid; i < 1536; i += 256) {
    int q = i & 3, dw = (i >> 2) & 1, dh = (i >> 3) & 1, c = i >> 4;
    size_t g = ((((size_t)b * 96 + c) * 64 + h0 * 2 + dh) * 64 + w0 * 2 + dw) * 64 + t0 * 16 + q * 4;
    float4 v = *(const float4*)(x + g);
    float vv[4] = {v.x, v.y, v.z, v.w};
    int base = dh * 4 + dw * 2;
#pragma unroll
    for (int j = 0; j < 4; ++j) {
      int tl = q * 4 + j;
      Xs[((tl >> 1) * 8 + base + (tl & 1)) * KPAD + c] = f2bf(vv[j]);
    }
  }
  stage_chunk(wsw + 0 * 9216, Ws, tid);  // qkv chunk 0 in flight
  __syncthreads();

  bf16x8 aX[3];
#pragma unroll
  for (int kt = 0; kt < 3; ++kt)
    aX[kt] = *(const bf16x8*)(Xs + arow + kt * 32);

  // P2: QKV (3 chunks of 96 cols) -> R[col][tok] stride QPAD
  for (int cn = 0; cn < 3; ++cn) {
    __syncthreads();  // chunk cn staged
#pragma unroll
    for (int nt = 0; nt < 6; ++nt) {
      int col = cn * 96 + nt * 16 + mrow;
      float bias = qkv_b[col];
      f32x4 acc = {bias, bias, bias, bias};
#pragma unroll
      for (int kt = 0; kt < 3; ++kt) {
        bf16x8 bf = *(const bf16x8*)(Ws + (nt * 3 + kt) * 512 + lane * 8);
        acc = __builtin_amdgcn_mfma_f32_16x16x32_bf16(aX[kt], bf, acc, 0, 0, 0);
      }
#pragma unroll
      for (int r = 0; r < 4; ++r) R[col * QPAD + tokb + r] = f2bf(acc[r]);
    }
    __syncthreads();  // Ws reads + R writes done
    if (cn < 2) stage_chunk(wsw + (cn + 1) * 9216, Ws, tid);
  }

  // P3: attention. thread = (win, head, 2 query rows). Q cols 0..95, K 96.., V 192..
  {
    const int win = tid >> 5, head = (tid >> 2) & 7, r2 = (tid & 3) * 2;
    const ushort* Qb = R + (head * 12) * QPAD + win * 8;
    const ushort* Kb = R + (96 + head * 12) * QPAD + win * 8;
    const ushort* Vb = R + (192 + head * 12) * QPAD + win * 8;
    const float scale = 0.28867513459481287f;  // 1/sqrt(12)
    float q0[12], q1[12];
#pragma unroll
    for (int d = 0; d < 12; ++d) { q0[d] = bf2f(Qb[d * QPAD + r2]); q1[d] = bf2f(Qb[d * QPAD + r2 + 1]); }
    float s0[8], s1[8];
#pragma unroll
    for (int m = 0; m < 8; ++m) {
      float a0 = 0.f, a1 = 0.f;
#pragma unroll
      for (int d = 0; d < 12; ++d) {
        float kv = bf2f(Kb[d * QPAD + m]);
        a0 += q0[d] * kv; a1 += q1[d] * kv;
      }
      s0[m] = a0 * scale; s1[m] = a1 * scale;
    }
    float mx0 = s0[0], mx1 = s1[0];
#pragma unroll
    for (int m = 1; m < 8; ++m) { mx0 = fmaxf(mx0, s0[m]); mx1 = fmaxf(mx1, s1[m]); }
    float sum0 = 0.f, sum1 = 0.f;
#pragma unroll
    for (int m = 0; m < 8; ++m) {
      s0[m] = __expf(s0[m] - mx0); sum0 += s0[m];
      s1[m] = __expf(s1[m] - mx1); sum1 += s1[m];
    }
    float inv0 = 1.0f / sum0, inv1 = 1.0f / sum1;
    float o0[12] = {}, o1[12] = {};
#pragma unroll
    for (int m = 0; m < 8; ++m) {
      float p0 = s0[m] * inv0, p1 = s1[m] * inv1;
#pragma unroll
      for (int d = 0; d < 12; ++d) {
        float vv = bf2f(Vb[d * QPAD + m]);
        o0[d] += p0 * vv; o1[d] += p1 * vv;
      }
    }
    __syncthreads();  // ALL QKV reads complete before msg overwrites R
    int tr = win * 8 + r2;
#pragma unroll
    for (int d = 0; d < 12; ++d) {
      R[tr * KPAD + head * 12 + d] = f2bf(o0[d]);
      R[(tr + 1) * KPAD + head * 12 + d] = f2bf(o1[d]);
    }
  }
  stage_chunk(wsw + 3 * 9216, Ws, tid);  // merge_w
  __syncthreads();

  // P4: msg2 = msg @ merge_w + b  (in place; wave's rows only -> race-free)
  {
    bf16x8 aM[3];
#pragma unroll
    for (int kt = 0; kt < 3; ++kt) aM[kt] = *(const bf16x8*)(R + arow + kt * 32);
#pragma unroll
    for (int nt = 0; nt < 6; ++nt) {
      int col = nt * 16 + mrow;
      float bias = merge_b[col];
      f32x4 acc = {bias, bias, bias, bias};
#pragma unroll
      for (int kt = 0; kt < 3; ++kt) {
        bf16x8 bf = *(const bf16x8*)(Ws + (nt * 3 + kt) * 512 + lane * 8);
        acc = __builtin_amdgcn_mfma_f32_16x16x32_bf16(aM[kt], bf, acc, 0, 0, 0);
      }
#pragma unroll
      for (int r = 0; r < 4; ++r) R[(tokb + r) * KPAD + col] = f2bf(acc[r]);
    }
  }
  __syncthreads();
  stage_chunk(wsw + 4 * 9216, Ws, tid);  // w1a
  __syncthreads();

  // P5: hmid = gelu(X@w1a + msg2@w1b + b1) -> R[6656 + tok*KPAD + col]
  {
    bf16x8 aX2[3];
#pragma unroll
    for (int kt = 0; kt < 3; ++kt) aX2[kt] = *(const bf16x8*)(Xs + arow + kt * 32);
    f32x4 accH[6];
#pragma unroll
    for (int nt = 0; nt < 6; ++nt) {
      int col = nt * 16 + mrow;
      float bias = b1[col];
      f32x4 acc = {bias, bias, bias, bias};
#pragma unroll
      for (int kt = 0; kt < 3; ++kt) {
        bf16x8 bf = *(const bf16x8*)(Ws + (nt * 3 + kt) * 512 + lane * 8);
        acc = __builtin_amdgcn_mfma_f32_16x16x32_bf16(aX2[kt], bf, acc, 0, 0, 0);
      }
      accH[nt] = acc;
    }
    __syncthreads();  // w1a reads done
    stage_chunk(wsw + 5 * 9216, Ws, tid);  // w1b
    bf16x8 aM2[3];
#pragma unroll
    for (int kt = 0; kt < 3; ++kt) aM2[kt] = *(const bf16x8*)(R + arow + kt * 32);
    __syncthreads();  // w1b staged
#pragma unroll
    for (int nt = 0; nt < 6; ++nt) {
      f32x4 acc = accH[nt];
#pragma unroll
      for (int kt = 0; kt < 3; ++kt) {
        bf16x8 bf = *(const bf16x8*)(Ws + (nt * 3 + kt) * 512 + lane * 8);
        acc = __builtin_amdgcn_mfma_f32_16x16x32_bf16(aM2[kt], bf, acc, 0, 0, 0);
      }
      int col = nt * 16 + mrow;
#pragma unroll
      for (int r = 0; r < 4; ++r) {
        float h = acc[r];
        float gel = 0.5f * h * (1.0f + erff(h * 0.70710678118654752f));
        R[6656 + (tokb + r) * KPAD + col] = f2bf(gel);
      }
    }
  }
  __syncthreads();
  stage_chunk(wsw + 6 * 9216, Ws, tid);  // w2
  __syncthreads();

  // P6: out = hmid @ w2 + b2 -> R[col*OPAD + tok]  (over dead msg region)
  {
    bf16x8 aH[3];
#pragma unroll
    for (int kt = 0; kt < 3; ++kt) aH[kt] = *(const bf16x8*)(R + 6656 + arow + kt * 32);
#pragma unroll
    for (int nt = 0; nt < 6; ++nt) {
      int col = nt * 16 + mrow;
      float bias = b2[col];
      f32x4 acc = {bias, bias, bias, bias};
#pragma unroll
      for (int kt = 0; kt < 3; ++kt) {
        bf16x8 bf = *(const bf16x8*)(Ws + (nt * 3 + kt) * 512 + lane * 8);
        acc = __builtin_amdgcn_mfma_f32_16x16x32_bf16(aH[kt], bf, acc, 0, 0, 0);
      }
#pragma unroll
      for (int r = 0; r < 4; ++r) R[col * OPAD + tokb + r] = f2bf(acc[r]);
    }
  }
  __syncthreads();

  // P7: coalesced float4 store along t
  for (int i = tid; i < 1536; i += 256) {
    int q = i & 3, dw = (i >> 2) & 1, dh = (i >> 3) & 1, c = i >> 4;
    float vv[4];
#pragma unroll
    for (int j = 0; j < 4; ++j) {
      int tl = q * 4 + j;
      vv[j] = bf2f(R[c * OPAD + (tl >> 1) * 8 + dh * 4 + dw * 2 + (tl & 1)]);
    }
    float4 v = {vv[0], vv[1], vv[2], vv[3]};
    size_t g = ((((size_t)b * 96 + c) * 64 + h0 * 2 + dh) * 64 + w0 * 2 + dw) * 64 + t0 * 16 + q * 4;
    *(float4*)(out + g) = v;
  }
}

extern "C" void kernel_launch(void* const* d_in, const int* in_sizes, int n_in,
                              void* d_out, int out_size, void* d_ws, size_t ws_size,
                              hipStream_t stream) {
  const float* x = (const float*)d_in[0];
  const float* qkv_w = (const float*)d_in[1];
  const float* qkv_b = (const float*)d_in[2];
  const float* merge_w = (const float*)d_in[3];
  const float* merge_b = (const float*)d_in[4];
  const float* w1 = (const float*)d_in[5];
  const float* b1 = (const float*)d_in[6];
  const float* w2 = (const float*)d_in[7];
  const float* b2 = (const float*)d_in[8];
  ushort* wsw = (ushort*)d_ws;  // needs 129024 B
  swizzle_w<<<dim3(32), dim3(256), 0, stream>>>(qkv_w, merge_w, w1, w2, wsw);
  // grid: B(2) x h0(32) x w0(32) x t0(4) = 8192 blocks
  swin_mfma<<<dim3(8192), dim3(256), 0, stream>>>(
      x, qkv_b, merge_b, b1, b2, wsw, (float*)d_out);
}